// Round 1
// baseline (873.600 us; speedup 1.0000x reference)
//
#include <hip/hip_runtime.h>

#define BATCH  262144
#define N_FEAT 256
#define N_INT  255
#define N_LEAF 256
#define ROWS   64
#define THREADS 256

// Fully-unrolled DFS over one depth-2 subtree (local depths J=0..5 <-> global
// depths 2..7). prefix is compile-time-propagated per inlined call site, so
// all LDS offsets fold to ds_read immediates off a runtime base — no scratch.
template<int J>
__device__ __forceinline__ float dfs(const float* __restrict__ row,
                                     int s, int prefix, float p,
                                     const float* __restrict__ leaf) {
  if constexpr (J == 6) {
    return p * leaf[(s << 6) + prefix];
  } else {
    int node = ((1 << (J + 2)) - 1) + (s << J) + prefix;  // heap index
    float w = row[node];
    return dfs<J + 1>(row, s, (prefix << 1),     p * (1.0f - w), leaf)
         + dfs<J + 1>(row, s, (prefix << 1) | 1, p * w,          leaf);
  }
}

__global__ __launch_bounds__(THREADS, 2) void sdt_kernel(
    const float* __restrict__ x,
    const float* __restrict__ split_cond,
    const float* __restrict__ u,
    const float* __restrict__ leaf_values,
    const int* __restrict__ split_idx,
    float* __restrict__ out)
{
  // 64 rows x 257 (pad +1: phase-2 reads become (lane + c) % 32 -> 2-way, free)
  __shared__ float s_w[ROWS][N_FEAT + 1];
  __shared__ float s_leaf[N_LEAF];
  __shared__ float s_cond[N_INT + 1];
  __shared__ int   s_idx[N_INT + 1];
  __shared__ float s_acc[4][ROWS];

  const int tid  = threadIdx.x;
  const int row0 = blockIdx.x * ROWS;

  s_leaf[tid] = leaf_values[tid];
  if (tid < N_INT) {
    s_cond[tid] = split_cond[tid];
    s_idx[tid]  = split_idx[tid];
  }
  __syncthreads();

  // ---- Phase 1: thread = node, loop over the tile's 64 rows. ----
  // u loads: lanes cover contiguous float2s -> 512 B/wave coalesced.
  // x gather: whole block shares one x row per iter -> L1-resident.
  if (tid < N_INT) {
    const int   node = tid;
    const float sc   = s_cond[node];
    const int   si   = s_idx[node];
    const float2* up = (const float2*)(u + (size_t)row0 * (2 * N_INT)) + node;
    const float*  xp = x + (size_t)row0 * N_FEAT + si;
    #pragma unroll 4
    for (int r = 0; r < ROWS; ++r) {
      float2 uv = up[(size_t)r * N_INT];
      float  xv = xp[(size_t)r * N_FEAT];
      float u0 = fminf(fmaxf(uv.x, 1e-10f), 1.0f);
      float u1 = fminf(fmaxf(uv.y, 1e-10f), 1.0f);
      float g0 = -__logf(-__logf(u0));          // Gumbel(0,1)
      float g1 = -__logf(-__logf(u1));
      float z  = (xv - sc) + (g0 - g1);
      float w  = 1.0f / (1.0f + __expf(-z));    // sigmoid
      s_w[r][node] = w;
    }
  }
  __syncthreads();

  // ---- Phase 2: thread = (subtree s, row r); contract tree from LDS. ----
  {
    const int s = tid >> 6;   // wave-uniform: wave k handles subtree k
    const int r = tid & 63;
    const float* row = &s_w[r][0];
    float w0 = row[0];                 // depth-0 node
    float f0 = (s & 2) ? w0 : (1.0f - w0);
    float w1 = row[1 + (s >> 1)];      // depth-1 node
    float f1 = (s & 1) ? w1 : (1.0f - w1);
    s_acc[s][r] = dfs<0>(row, s, 0, f0 * f1, s_leaf);
  }
  __syncthreads();

  if (tid < ROWS) {
    out[row0 + tid] = (s_acc[0][tid] + s_acc[1][tid])
                    + (s_acc[2][tid] + s_acc[3][tid]);
  }
}

extern "C" void kernel_launch(void* const* d_in, const int* in_sizes, int n_in,
                              void* d_out, int out_size, void* d_ws, size_t ws_size,
                              hipStream_t stream) {
  const float* x           = (const float*)d_in[0];
  const float* split_cond  = (const float*)d_in[1];
  const float* u           = (const float*)d_in[2];
  const float* leaf_values = (const float*)d_in[3];
  const int*   split_idx   = (const int*)d_in[4];
  float*       out         = (float*)d_out;

  sdt_kernel<<<dim3(BATCH / ROWS), dim3(THREADS), 0, stream>>>(
      x, split_cond, u, leaf_values, split_idx, out);
}